// Round 2
// baseline (12976.193 us; speedup 1.0000x reference)
//
#include <hip/hip_runtime.h>
#include <math.h>

#define E 8
#define S 6000
#define D 128
#define A 16
#define L 64
#define H 256
#define C 64
#define B 50
#define T 120
#define NSUB 2
#define FLAT 208      // L + A + D
#define RTOT 400      // E * B
#define RPB 4
#define NBLK (RTOT / RPB)
#define BGRP 10
#define NBG 5

#define DT 0.5f
#define SQDT 0.70710678118654752440f

#define GNT 4096
#define GYMIN (-128.0f)
#define GDY 0.0625f
#define GINVDY 16.0f

__device__ __forceinline__ float sigf(float x) { return 1.0f / (1.0f + __expf(-x)); }

// ---------------------------------------------------------------- g table
__global__ void gtab_kernel(const float* __restrict__ gw1, const float* __restrict__ gb1,
                            const float* __restrict__ gw2, const float* __restrict__ gb2,
                            float* __restrict__ tab) {
    int idx = blockIdx.x * blockDim.x + threadIdx.x;
    if (idx >= L * GNT) return;
    int l = idx / GNT, i = idx % GNT;
    float y = GYMIN + (float)i * GDY;
    const float* w1 = gw1 + l * H;
    const float* b1 = gb1 + l * H;
    const float* w2 = gw2 + l * H;
    float acc = gb2[l];
    #pragma unroll 4
    for (int h = 0; h < H; ++h) acc += w2[h] * sigf(y * w1[h] + b1[h]);
    tab[idx] = acc;
}

// ---------------------------------------------------------------- weight packing
// src (K, Hn) row-major [k][h]  ->  dst float4-chunked: dst[((k/4)*Hn + h)*4 + (k%4)]
__global__ void packQ_kernel(const float* __restrict__ src, float* __restrict__ dst, int K, int Hn) {
    int idx = blockIdx.x * 256 + threadIdx.x;
    if (idx >= K * Hn) return;
    int k = idx / Hn, h = idx % Hn;
    dst[(((k >> 2) * Hn + h) << 2) + (k & 3)] = src[idx];
}

// act_w first L rows per e: dst[e*4096 + ((k/4)*64 + l)*4 + (k%4)] = aw[(e*FLAT + k)*64 + l]
__global__ void packA_kernel(const float* __restrict__ aw, float* __restrict__ dst) {
    int idx = blockIdx.x * 256 + threadIdx.x;
    if (idx >= E * L * L) return;
    int e = idx >> 12;
    int rem = idx & 4095;
    int k = rem >> 6, l = rem & 63;
    dst[(e << 12) + ((((k >> 2) << 6) + l) << 2) + (k & 3)] = aw[((size_t)e * FLAT + k) * L + l];
}

// ---------------------------------------------------------------- encoder + KL (+ z0 at t=0)
__global__ __launch_bounds__(256) void enc_kernel(const float* __restrict__ xs, const float* __restrict__ z0n,
                           const float* __restrict__ ew1, const float* __restrict__ eb1,
                           const float* __restrict__ ew2, const float* __restrict__ eb2,
                           const float* __restrict__ qw,  const float* __restrict__ qb,
                           const float* __restrict__ pm,  const float* __restrict__ pl,
                           float* __restrict__ z0buf, float* __restrict__ logqp0p) {
    int bid = blockIdx.x;            // (t*E + e)*NBG + bg
    int bg = bid % NBG; int te = bid / NBG; int e = te % E; int t = te / E;
    int tid = threadIdx.x;           // 256
    __shared__ float xsh[BGRP][D];
    __shared__ float c1s[BGRP][H];
    __shared__ float part[4][C][BGRP];
    __shared__ float ctxs[BGRP][C];
    __shared__ float qs[BGRP][2 * L];

    for (int i = tid; i < BGRP * D; i += 256) {
        int j = i / D, d = i % D;
        xsh[j][d] = xs[((size_t)e * S + (size_t)t * B + bg * BGRP + j) * D + d];
    }
    __syncthreads();
    {   // c1 = sigmoid(x @ ew1 + eb1), h = tid
        float bias = eb1[e * H + tid];
        float acc[BGRP];
        #pragma unroll
        for (int j = 0; j < BGRP; ++j) acc[j] = bias;
        const float* w = ew1 + (size_t)e * D * H + tid;
        #pragma unroll 4
        for (int d = 0; d < D; ++d) {
            float wv = w[(size_t)d * H];
            #pragma unroll
            for (int j = 0; j < BGRP; ++j) acc[j] += xsh[j][d] * wv;
        }
        #pragma unroll
        for (int j = 0; j < BGRP; ++j) c1s[j][tid] = sigf(acc[j]);
    }
    __syncthreads();
    {   // ctx partial: c = tid&63, kq = tid>>6
        int c = tid & 63, kq = tid >> 6;
        float acc[BGRP];
        #pragma unroll
        for (int j = 0; j < BGRP; ++j) acc[j] = 0.f;
        const float* w = ew2 + (size_t)e * H * C + c;
        #pragma unroll 4
        for (int h = kq * 64; h < kq * 64 + 64; ++h) {
            float wv = w[(size_t)h * C];
            #pragma unroll
            for (int j = 0; j < BGRP; ++j) acc[j] += c1s[j][h] * wv;
        }
        #pragma unroll
        for (int j = 0; j < BGRP; ++j) part[kq][c][j] = acc[j];
    }
    __syncthreads();
    if (tid < C) {
        float bias = eb2[e * C + tid];
        #pragma unroll
        for (int j = 0; j < BGRP; ++j)
            ctxs[j][tid] = part[0][tid][j] + part[1][tid][j] + part[2][tid][j] + part[3][tid][j] + bias;
    }
    __syncthreads();
    if (tid < 2 * L) {
        float bias = qb[e * 2 * L + tid];
        float acc[BGRP];
        #pragma unroll
        for (int j = 0; j < BGRP; ++j) acc[j] = bias;
        const float* w = qw + (size_t)e * C * 2 * L + tid;
        #pragma unroll 4
        for (int c = 0; c < C; ++c) {
            float wv = w[(size_t)c * 2 * L];
            #pragma unroll
            for (int j = 0; j < BGRP; ++j) acc[j] += ctxs[j][c] * wv;
        }
        #pragma unroll
        for (int j = 0; j < BGRP; ++j) qs[j][tid] = acc[j];
    }
    __syncthreads();
    if (tid < L) {
        int l = tid;
        float kacc = 0.f;
        float m = pm[e * L + l], ls = pl[e * L + l];
        float inv2e = 1.0f / (2.0f * __expf(2.0f * ls));
        #pragma unroll
        for (int j = 0; j < BGRP; ++j) {
            float qm = qs[j][l], ql = qs[j][L + l];
            if (t == 0) {
                int b = bg * BGRP + j;
                float n = z0n[((size_t)e * B + b) * L + l];
                z0buf[((size_t)e * B + b) * L + l] = qm + __expf(ql) * n;
            }
            float dq = qm - m;
            kacc += ls - ql + (__expf(2.f * ql) + dq * dq) * inv2e - 0.5f;
        }
        #pragma unroll
        for (int off = 32; off; off >>= 1) kacc += __shfl_xor(kacc, off);
        if (l == 0) logqp0p[bid] = kacc / (float)B;
    }
}

// ---------------------------------------------------------------- action/x part of z_enc
__global__ __launch_bounds__(64) void ax_kernel(const float* __restrict__ xs, const float* __restrict__ actions,
                          const float* __restrict__ aw, const float* __restrict__ ab,
                          float* __restrict__ ax) {
    int bid = blockIdx.x;            // (t*E + e)*NBG + bg
    int bg = bid % NBG; int te = bid / NBG; int e = te % E; int t = te / E;
    int tid = threadIdx.x;           // 64
    __shared__ float xrow[BGRP][D];
    __shared__ float arow[BGRP][A];
    for (int i = tid; i < BGRP * D; i += 64) {
        int j = i / D, d = i % D;
        xrow[j][d] = xs[((size_t)e * S + (size_t)t * B + bg * BGRP + j) * D + d];
    }
    for (int i = tid; i < BGRP * A; i += 64) {
        int j = i / A, a = i % A;
        arow[j][a] = actions[((size_t)e * S + (size_t)t * B + bg * BGRP + j) * A + a];
    }
    __syncthreads();
    int l = tid;
    float acc[BGRP];
    float bias = ab[e * L + l];
    #pragma unroll
    for (int j = 0; j < BGRP; ++j) acc[j] = bias;
    const float* awp = aw + ((size_t)e * FLAT + L) * L + l;
    #pragma unroll 4
    for (int a = 0; a < A; ++a) {
        float wv = awp[(size_t)a * L];
        #pragma unroll
        for (int j = 0; j < BGRP; ++j) acc[j] += arow[j][a] * wv;
    }
    const float* xwp = aw + ((size_t)e * FLAT + L + A) * L + l;
    #pragma unroll 4
    for (int d = 0; d < D; ++d) {
        float wv = xwp[(size_t)d * L];
        #pragma unroll
        for (int j = 0; j < BGRP; ++j) acc[j] += xrow[j][d] * wv;
    }
    size_t rbase = (size_t)t * RTOT + e * B + bg * BGRP;
    #pragma unroll
    for (int j = 0; j < BGRP; ++j) ax[(rbase + j) * L + l] = acc[j];
}

// ---------------------------------------------------------------- drift_all (device)
__device__ __forceinline__ void drift(
    int tid, const float (*__restrict__ y)[L],
    float (*__restrict__ fzo)[L], float (*__restrict__ gzo)[L], float* __restrict__ lfo,
    float (*__restrict__ h1)[RPB][H], float (*__restrict__ h2)[RPB][H],
    float (*__restrict__ fh)[RPB][L],
    const float* __restrict__ pa, const float* __restrict__ fb1, const float* __restrict__ hb1,
    const float* __restrict__ pb, const float* __restrict__ fb2, const float* __restrict__ hb2,
    const float* __restrict__ pc, const float* __restrict__ fb3, const float* __restrict__ hb3,
    const float* __restrict__ gtab)
{
    int h0  = tid & 63;
    int row = (tid >> 6) & 3;
    int net = tid >> 8;              // 0..1 (512 threads, wave-uniform)
    {   // stage a: (64 -> 256), 4 outputs per thread
        const float4* wp = (const float4*)pa + (net << 12) + h0;
        const float4* yp = (const float4*)(y[row]);
        const float* bp = net ? hb1 : fb1;
        float a0 = bp[h0], a1 = bp[h0 + 64], a2 = bp[h0 + 128], a3 = bp[h0 + 192];
        float b0 = 0.f, b1 = 0.f, b2 = 0.f, b3 = 0.f;
        #pragma unroll
        for (int q = 0; q < 16; ++q) {
            float4 u  = yp[q];
            float4 w0 = wp[q * 256], w1 = wp[q * 256 + 64], w2 = wp[q * 256 + 128], w3 = wp[q * 256 + 192];
            a0 += w0.x * u.x; b0 += w0.y * u.y; a0 += w0.z * u.z; b0 += w0.w * u.w;
            a1 += w1.x * u.x; b1 += w1.y * u.y; a1 += w1.z * u.z; b1 += w1.w * u.w;
            a2 += w2.x * u.x; b2 += w2.y * u.y; a2 += w2.z * u.z; b2 += w2.w * u.w;
            a3 += w3.x * u.x; b3 += w3.y * u.y; a3 += w3.z * u.z; b3 += w3.w * u.w;
        }
        h1[net][row][h0]       = sigf(a0 + b0);
        h1[net][row][h0 + 64]  = sigf(a1 + b1);
        h1[net][row][h0 + 128] = sigf(a2 + b2);
        h1[net][row][h0 + 192] = sigf(a3 + b3);
    }
    __syncthreads();
    {   // stage b: (256 -> 256), 4 outputs per thread
        const float4* wp = (const float4*)pb + (net << 14) + h0;
        const float4* ip = (const float4*)(h1[net][row]);
        const float* bp = net ? hb2 : fb2;
        float a0 = bp[h0], a1 = bp[h0 + 64], a2 = bp[h0 + 128], a3 = bp[h0 + 192];
        float b0 = 0.f, b1 = 0.f, b2 = 0.f, b3 = 0.f;
        #pragma unroll 4
        for (int q = 0; q < 64; ++q) {
            float4 u  = ip[q];
            float4 w0 = wp[q * 256], w1 = wp[q * 256 + 64], w2 = wp[q * 256 + 128], w3 = wp[q * 256 + 192];
            a0 += w0.x * u.x; b0 += w0.y * u.y; a0 += w0.z * u.z; b0 += w0.w * u.w;
            a1 += w1.x * u.x; b1 += w1.y * u.y; a1 += w1.z * u.z; b1 += w1.w * u.w;
            a2 += w2.x * u.x; b2 += w2.y * u.y; a2 += w2.z * u.z; b2 += w2.w * u.w;
            a3 += w3.x * u.x; b3 += w3.y * u.y; a3 += w3.z * u.z; b3 += w3.w * u.w;
        }
        h2[net][row][h0]       = sigf(a0 + b0);
        h2[net][row][h0 + 64]  = sigf(a1 + b1);
        h2[net][row][h0 + 128] = sigf(a2 + b2);
        h2[net][row][h0 + 192] = sigf(a3 + b3);
    }
    __syncthreads();
    if (tid < 256) {   // stage c: (256 -> 64), 2 outputs per thread
        int l0   = tid & 31;
        int crow = (tid >> 5) & 3;
        int cnet = tid >> 7;
        const float4* wp = (const float4*)pc + (cnet << 12) + l0;
        const float4* ip = (const float4*)(h2[cnet][crow]);
        float a0 = 0.f, b0 = 0.f, a1 = 0.f, b1 = 0.f;
        #pragma unroll 4
        for (int q = 0; q < 64; ++q) {
            float4 u  = ip[q];
            float4 w0 = wp[q * 64], w1 = wp[q * 64 + 32];
            a0 += w0.x * u.x; b0 += w0.y * u.y; a0 += w0.z * u.z; b0 += w0.w * u.w;
            a1 += w1.x * u.x; b1 += w1.y * u.y; a1 += w1.z * u.z; b1 += w1.w * u.w;
        }
        fh[cnet][crow][l0]      = a0 + b0;
        fh[cnet][crow][l0 + 32] = a1 + b1;
    }
    __syncthreads();
    if (tid < 256) {   // finalize: bias, g table, u, lf
        int l = tid & 63;
        int row2 = tid >> 6;
        float fv = fh[0][row2][l] + fb3[l];
        float hv = fh[1][row2][l] + hb3[l];
        float yl = y[row2][l];
        float x = (yl - GYMIN) * GINVDY;
        x = fminf(fmaxf(x, 0.0f), (float)(GNT - 2) + 0.999f);
        int i = (int)x;
        float fr = x - (float)i;
        const float* tl = gtab + ((size_t)l << 12);
        float gv = tl[i] * (1.0f - fr) + tl[i + 1] * fr;
        float u = (fv - hv) / gv;
        fzo[row2][l] = fv;
        gzo[row2][l] = gv;
        float us = u * u;
        #pragma unroll
        for (int off = 32; off; off >>= 1) us += __shfl_xor(us, off);
        if (l == 0) lfo[row2] = 0.5f * us;
    }
    __syncthreads();
}

// ---------------------------------------------------------------- sequential SDE loop
__global__ __launch_bounds__(512) void seq_kernel(
    const float* __restrict__ awPk, const float* __restrict__ dW,
    const float* __restrict__ z0buf, const float* __restrict__ axbuf,
    const float* __restrict__ pa, const float* __restrict__ fb1, const float* __restrict__ hb1,
    const float* __restrict__ pb, const float* __restrict__ fb2, const float* __restrict__ hb2,
    const float* __restrict__ pc, const float* __restrict__ fb3, const float* __restrict__ hb3,
    const float* __restrict__ gtab, float* __restrict__ z_all, float* __restrict__ rowlr)
{
    __shared__ __align__(16) float Z[RPB][L], zc[RPB][L], zhA[RPB][L], zhB[RPB][L];
    __shared__ float dwS[RPB][L];
    __shared__ __align__(16) float fzb[2][RPB][L], gzb[2][RPB][L];
    __shared__ __align__(16) float h1[2][RPB][H], h2[2][RPB][H];
    __shared__ float fh[2][RPB][L];
    __shared__ float lfb[2][RPB], lcS[RPB], lrsum[RPB];

    int tid = threadIdx.x;
    int r_base = blockIdx.x * RPB;
    int row = (tid >> 6) & 3;
    int l = tid & 63;
    int r_glob = r_base + row;
    int e_row = r_glob / B;

    if (tid < 256) Z[row][l] = z0buf[(size_t)r_glob * L + l];
    if (tid < RPB) lrsum[tid] = 0.f;
    __syncthreads();

    const float4* aw4 = (const float4*)awPk + (e_row << 10) + l;

    for (int t = 0; t < T; ++t) {
        if (tid < 256) {   // z_enc = z_in @ act_w[:, :L] + precomputed action/x part
            float a = axbuf[((size_t)t * RTOT + r_glob) * L + l];
            float b = 0.f;
            const float4* zp = (const float4*)(Z[row]);
            #pragma unroll
            for (int q = 0; q < 16; ++q) {
                float4 w = aw4[q * 64];
                float4 u = zp[q];
                a += w.x * u.x; b += w.y * u.y; a += w.z * u.z; b += w.w * u.w;
            }
            float v = a + b;
            zc[row][l] = v;
            zhA[row][l] = v;
        }
        if (tid < RPB) lcS[tid] = 0.f;
        __syncthreads();

        drift(tid, zc, fzb[0], gzb[0], lfb[0], h1, h2, fh,
              pa, fb1, hb1, pb, fb2, hb2, pc, fb3, hb3, gtab);

        float (*zh)[L] = zhA;
        float (*zt)[L] = zhB;
        int cur = 0;
        #pragma unroll
        for (int k = 0; k < NSUB; ++k) {
            int nxt = cur ^ 1;
            if (tid < 256) {
                float dwv = dW[((size_t)(t * NSUB + k) * RTOT + r_base) * L + tid] * SQDT;
                dwS[row][l] = dwv;
                zt[row][l] = 2.f * zc[row][l] - zh[row][l]
                           + fzb[cur][row][l] * DT + gzb[cur][row][l] * dwv;
            }
            __syncthreads();
            drift(tid, zt, fzb[nxt], gzb[nxt], lfb[nxt], h1, h2, fh,
                  pa, fb1, hb1, pb, fb2, hb2, pc, fb3, hb3, gtab);
            if (tid < 256) {
                zc[row][l] += 0.5f * (fzb[cur][row][l] + fzb[nxt][row][l]) * DT
                            + 0.5f * (gzb[cur][row][l] + gzb[nxt][row][l]) * dwS[row][l];
            }
            if (tid < RPB) lcS[tid] += 0.5f * (lfb[cur][tid] + lfb[nxt][tid]) * DT;
            { float (*tmp)[L] = zh; zh = zt; zt = tmp; }
            cur = nxt;
            __syncthreads();
        }
        if (tid < 256) {
            Z[row][l] = zc[row][l];
            z_all[((size_t)t * RTOT + r_glob) * L + l] = zc[row][l];
        }
        if (tid < RPB) lrsum[tid] += lcS[tid];
        __syncthreads();
    }
    if (tid < RPB) rowlr[r_base + tid] = lrsum[tid];
}

// ---------------------------------------------------------------- projection
__global__ __launch_bounds__(256) void proj_kernel(const float* __restrict__ z_all,
                            const float* __restrict__ pw1, const float* __restrict__ pb1,
                            const float* __restrict__ pw2, const float* __restrict__ pb2,
                            const float* __restrict__ pw3, const float* __restrict__ pb3,
                            float* __restrict__ out) {
    int bid = blockIdx.x;            // (t*E + e)*NBG + bg
    int bg = bid % NBG; int te = bid / NBG; int e = te % E; int t = te / E;
    int tid = threadIdx.x;           // 256
    __shared__ float zs[BGRP][L];
    __shared__ float p1s[BGRP][H];
    __shared__ float p2s[BGRP][H];
    __shared__ float part3[D][BGRP];
    size_t rbase = (size_t)t * RTOT + e * B + bg * BGRP;
    for (int i = tid; i < BGRP * L; i += 256) {
        int j = i >> 6, ll = i & 63;
        zs[j][ll] = z_all[(rbase + j) * L + ll];
    }
    __syncthreads();
    {
        float bias = pb1[e * H + tid];
        float acc[BGRP];
        #pragma unroll
        for (int j = 0; j < BGRP; ++j) acc[j] = bias;
        const float* w = pw1 + (size_t)e * L * H + tid;
        #pragma unroll 4
        for (int k = 0; k < L; ++k) {
            float wv = w[(size_t)k * H];
            #pragma unroll
            for (int j = 0; j < BGRP; ++j) acc[j] += zs[j][k] * wv;
        }
        #pragma unroll
        for (int j = 0; j < BGRP; ++j) p1s[j][tid] = sigf(acc[j]);
    }
    __syncthreads();
    {
        float bias = pb2[e * H + tid];
        float acc[BGRP];
        #pragma unroll
        for (int j = 0; j < BGRP; ++j) acc[j] = bias;
        const float* w = pw2 + (size_t)e * H * H + tid;
        #pragma unroll 4
        for (int k = 0; k < H; ++k) {
            float wv = w[(size_t)k * H];
            #pragma unroll
            for (int j = 0; j < BGRP; ++j) acc[j] += p1s[j][k] * wv;
        }
        #pragma unroll
        for (int j = 0; j < BGRP; ++j) p2s[j][tid] = sigf(acc[j]);
    }
    __syncthreads();
    float acc3[BGRP];
    {
        int dd = tid & 127, kh = tid >> 7;
        #pragma unroll
        for (int j = 0; j < BGRP; ++j) acc3[j] = 0.f;
        const float* w = pw3 + (size_t)e * H * D + dd;
        #pragma unroll 4
        for (int k = kh * 128; k < kh * 128 + 128; ++k) {
            float wv = w[(size_t)k * D];
            #pragma unroll
            for (int j = 0; j < BGRP; ++j) acc3[j] += p2s[j][k] * wv;
        }
        if (kh == 1) {
            #pragma unroll
            for (int j = 0; j < BGRP; ++j) part3[dd][j] = acc3[j];
        }
    }
    __syncthreads();
    if (tid < D) {
        float bias = pb3[e * D + tid];
        #pragma unroll
        for (int j = 0; j < BGRP; ++j) {
            out[8 + ((size_t)e * S + (size_t)t * B + bg * BGRP + j) * D + tid]
                = acc3[j] + part3[tid][j] + bias;
        }
    }
}

// ---------------------------------------------------------------- final combine
__global__ void fin_kernel(const float* __restrict__ logqp0p, const float* __restrict__ rowlr,
                           float* __restrict__ out) {
    int e = threadIdx.x;
    if (e < E) {
        float acc = 0.f;
        for (int t = 0; t < T; ++t)
            for (int bg = 0; bg < NBG; ++bg)
                acc += logqp0p[(t * E + e) * NBG + bg];
        float s = 0.f;
        for (int b = 0; b < B; ++b) s += rowlr[e * B + b];
        out[e] = acc + s / (float)B;
    }
}

extern "C" void kernel_launch(void* const* d_in, const int* in_sizes, int n_in,
                              void* d_out, int out_size, void* d_ws, size_t ws_size,
                              hipStream_t stream) {
    const float* xs      = (const float*)d_in[0];
    const float* actions = (const float*)d_in[1];
    const float* z0n     = (const float*)d_in[2];
    const float* dWp     = (const float*)d_in[3];
    const float* ew1     = (const float*)d_in[4];
    const float* eb1     = (const float*)d_in[5];
    const float* ew2     = (const float*)d_in[6];
    const float* eb2     = (const float*)d_in[7];
    const float* qw      = (const float*)d_in[8];
    const float* qb      = (const float*)d_in[9];
    const float* aw      = (const float*)d_in[10];
    const float* ab      = (const float*)d_in[11];
    const float* fw1     = (const float*)d_in[12];
    const float* fb1     = (const float*)d_in[13];
    const float* fw2     = (const float*)d_in[14];
    const float* fb2     = (const float*)d_in[15];
    const float* fw3     = (const float*)d_in[16];
    const float* fb3     = (const float*)d_in[17];
    const float* hw1     = (const float*)d_in[18];
    const float* hb1     = (const float*)d_in[19];
    const float* hw2     = (const float*)d_in[20];
    const float* hb2     = (const float*)d_in[21];
    const float* hw3     = (const float*)d_in[22];
    const float* hb3     = (const float*)d_in[23];
    const float* gw1     = (const float*)d_in[24];
    const float* gb1     = (const float*)d_in[25];
    const float* gw2     = (const float*)d_in[26];
    const float* gb2     = (const float*)d_in[27];
    const float* pw1     = (const float*)d_in[28];
    const float* pb1     = (const float*)d_in[29];
    const float* pw2     = (const float*)d_in[30];
    const float* pb2     = (const float*)d_in[31];
    const float* pw3     = (const float*)d_in[32];
    const float* pb3     = (const float*)d_in[33];
    const float* pm      = (const float*)d_in[34];
    const float* pl      = (const float*)d_in[35];

    float* ws      = (float*)d_ws;
    float* z0buf   = ws;                       // E*B*L            = 25600
    float* axbuf   = z0buf + 25600;            // T*RTOT*L         = 3072000
    float* z_all   = axbuf + 3072000;          // T*RTOT*L         = 3072000
    float* logqp0p = z_all + 3072000;          // T*E*NBG          = 4800
    float* rowlr   = logqp0p + 4800;           // RTOT             = 400
    float* gtab    = rowlr + 400;              // L*GNT            = 262144
    float* pa      = gtab + 262144;            // 2*64*256         = 32768
    float* pb      = pa + 32768;               // 2*256*256        = 131072
    float* pc      = pb + 131072;              // 2*256*64         = 32768
    float* awPk    = pc + 32768;               // E*64*64          = 32768
    float* out     = (float*)d_out;

    packQ_kernel<<<64, 256, 0, stream>>>(fw1, pa, 64, 256);
    packQ_kernel<<<64, 256, 0, stream>>>(hw1, pa + 16384, 64, 256);
    packQ_kernel<<<256, 256, 0, stream>>>(fw2, pb, 256, 256);
    packQ_kernel<<<256, 256, 0, stream>>>(hw2, pb + 65536, 256, 256);
    packQ_kernel<<<64, 256, 0, stream>>>(fw3, pc, 256, 64);
    packQ_kernel<<<64, 256, 0, stream>>>(hw3, pc + 16384, 256, 64);
    packA_kernel<<<128, 256, 0, stream>>>(aw, awPk);
    gtab_kernel<<<1024, 256, 0, stream>>>(gw1, gb1, gw2, gb2, gtab);
    enc_kernel<<<T * E * NBG, 256, 0, stream>>>(xs, z0n, ew1, eb1, ew2, eb2, qw, qb, pm, pl, z0buf, logqp0p);
    ax_kernel<<<T * E * NBG, 64, 0, stream>>>(xs, actions, aw, ab, axbuf);
    seq_kernel<<<NBLK, 512, 0, stream>>>(awPk, dWp, z0buf, axbuf,
                                         pa, fb1, hb1, pb, fb2, hb2, pc, fb3, hb3,
                                         gtab, z_all, rowlr);
    proj_kernel<<<T * E * NBG, 256, 0, stream>>>(z_all, pw1, pb1, pw2, pb2, pw3, pb3, out);
    fin_kernel<<<1, 64, 0, stream>>>(logqp0p, rowlr, out);
}

// Round 3
// 4584.062 us; speedup vs baseline: 2.8307x; 2.8307x over previous
//
#include <hip/hip_runtime.h>
#include <math.h>

#define E 8
#define S 6000
#define D 128
#define A 16
#define L 64
#define H 256
#define C 64
#define B 50
#define T 120
#define NSUB 2
#define FLAT 208      // L + A + D
#define RTOT 400      // E * B
#define RPB 16
#define NBLK (RTOT / RPB)   // 25
#define BGRP 10
#define NBG 5

#define DT 0.5f
#define SQDT 0.70710678118654752440f

#define GNT 4096
#define GYMIN (-128.0f)
#define GDY 0.0625f
#define GINVDY 16.0f

typedef __attribute__((ext_vector_type(8))) short bf16x8;
typedef __attribute__((ext_vector_type(4))) float f32x4;

#define MFMA16(a, b, c) __builtin_amdgcn_mfma_f32_16x16x32_bf16(a, b, c, 0, 0, 0)

__device__ __forceinline__ float sigf(float x) { return 1.0f / (1.0f + __expf(-x)); }

__device__ __forceinline__ unsigned short f2bf(float x) {
    union { float f; unsigned u; } v; v.f = x;
    unsigned r = (v.u + 0x7FFFu + ((v.u >> 16) & 1u)) >> 16;
    return (unsigned short)r;
}

// ---------------------------------------------------------------- g table
__global__ void gtab_kernel(const float* __restrict__ gw1, const float* __restrict__ gb1,
                            const float* __restrict__ gw2, const float* __restrict__ gb2,
                            float* __restrict__ tab) {
    int idx = blockIdx.x * blockDim.x + threadIdx.x;
    if (idx >= L * GNT) return;
    int l = idx / GNT, i = idx % GNT;
    float y = GYMIN + (float)i * GDY;
    const float* w1 = gw1 + l * H;
    const float* b1 = gb1 + l * H;
    const float* w2 = gw2 + l * H;
    float acc = gb2[l];
    #pragma unroll 4
    for (int h = 0; h < H; ++h) acc += w2[h] * sigf(y * w1[h] + b1[h]);
    tab[idx] = acc;
}

// ---------------------------------------------------------------- B-fragment pack (bf16)
// src fp32 [K][N] -> dst bf16 fragment order: dst[((n*(K/32)+kc)*64 + lane)*8 + j]
//   = src[kc*32 + (lane>>4)*8 + j][n*16 + (lane&15)]
__global__ void packB_kernel(const float* __restrict__ src, unsigned short* __restrict__ dst,
                             int K, int N) {
    int idx = blockIdx.x * 256 + threadIdx.x;
    if (idx >= K * N) return;
    int j = idx & 7;
    int lane = (idx >> 3) & 63;
    int t2 = idx >> 9;               // n*(K/32) + kc
    int KC = K >> 5;
    int kc = t2 % KC, n = t2 / KC;
    int k = (kc << 5) + ((lane >> 4) << 3) + j;
    int c = (n << 4) + (lane & 15);
    dst[idx] = f2bf(src[k * N + c]);
}

// act_w first L rows per e -> float4 chunks: dst[e*4096 + ((k/4)*64 + l)*4 + (k%4)]
__global__ void packA_kernel(const float* __restrict__ aw, float* __restrict__ dst) {
    int idx = blockIdx.x * 256 + threadIdx.x;
    if (idx >= E * L * L) return;
    int e = idx >> 12;
    int rem = idx & 4095;
    int k = rem >> 6, l = rem & 63;
    dst[(e << 12) + ((((k >> 2) << 6) + l) << 2) + (k & 3)] = aw[((size_t)e * FLAT + k) * L + l];
}

// ---------------------------------------------------------------- encoder + KL (+ z0 at t=0)
__global__ __launch_bounds__(256) void enc_kernel(const float* __restrict__ xs, const float* __restrict__ z0n,
                           const float* __restrict__ ew1, const float* __restrict__ eb1,
                           const float* __restrict__ ew2, const float* __restrict__ eb2,
                           const float* __restrict__ qw,  const float* __restrict__ qb,
                           const float* __restrict__ pm,  const float* __restrict__ pl,
                           float* __restrict__ z0buf, float* __restrict__ logqp0p) {
    int bid = blockIdx.x;            // (t*E + e)*NBG + bg
    int bg = bid % NBG; int te = bid / NBG; int e = te % E; int t = te / E;
    int tid = threadIdx.x;           // 256
    __shared__ float xsh[BGRP][D];
    __shared__ float c1s[BGRP][H];
    __shared__ float part[4][C][BGRP];
    __shared__ float ctxs[BGRP][C];
    __shared__ float qs[BGRP][2 * L];

    for (int i = tid; i < BGRP * D; i += 256) {
        int j = i / D, d = i % D;
        xsh[j][d] = xs[((size_t)e * S + (size_t)t * B + bg * BGRP + j) * D + d];
    }
    __syncthreads();
    {
        float bias = eb1[e * H + tid];
        float acc[BGRP];
        #pragma unroll
        for (int j = 0; j < BGRP; ++j) acc[j] = bias;
        const float* w = ew1 + (size_t)e * D * H + tid;
        #pragma unroll 4
        for (int d = 0; d < D; ++d) {
            float wv = w[(size_t)d * H];
            #pragma unroll
            for (int j = 0; j < BGRP; ++j) acc[j] += xsh[j][d] * wv;
        }
        #pragma unroll
        for (int j = 0; j < BGRP; ++j) c1s[j][tid] = sigf(acc[j]);
    }
    __syncthreads();
    {
        int c = tid & 63, kq = tid >> 6;
        float acc[BGRP];
        #pragma unroll
        for (int j = 0; j < BGRP; ++j) acc[j] = 0.f;
        const float* w = ew2 + (size_t)e * H * C + c;
        #pragma unroll 4
        for (int h = kq * 64; h < kq * 64 + 64; ++h) {
            float wv = w[(size_t)h * C];
            #pragma unroll
            for (int j = 0; j < BGRP; ++j) acc[j] += c1s[j][h] * wv;
        }
        #pragma unroll
        for (int j = 0; j < BGRP; ++j) part[kq][c][j] = acc[j];
    }
    __syncthreads();
    if (tid < C) {
        float bias = eb2[e * C + tid];
        #pragma unroll
        for (int j = 0; j < BGRP; ++j)
            ctxs[j][tid] = part[0][tid][j] + part[1][tid][j] + part[2][tid][j] + part[3][tid][j] + bias;
    }
    __syncthreads();
    if (tid < 2 * L) {
        float bias = qb[e * 2 * L + tid];
        float acc[BGRP];
        #pragma unroll
        for (int j = 0; j < BGRP; ++j) acc[j] = bias;
        const float* w = qw + (size_t)e * C * 2 * L + tid;
        #pragma unroll 4
        for (int c = 0; c < C; ++c) {
            float wv = w[(size_t)c * 2 * L];
            #pragma unroll
            for (int j = 0; j < BGRP; ++j) acc[j] += ctxs[j][c] * wv;
        }
        #pragma unroll
        for (int j = 0; j < BGRP; ++j) qs[j][tid] = acc[j];
    }
    __syncthreads();
    if (tid < L) {
        int l = tid;
        float kacc = 0.f;
        float m = pm[e * L + l], ls = pl[e * L + l];
        float inv2e = 1.0f / (2.0f * __expf(2.0f * ls));
        #pragma unroll
        for (int j = 0; j < BGRP; ++j) {
            float qm = qs[j][l], ql = qs[j][L + l];
            if (t == 0) {
                int b = bg * BGRP + j;
                float n = z0n[((size_t)e * B + b) * L + l];
                z0buf[((size_t)e * B + b) * L + l] = qm + __expf(ql) * n;
            }
            float dq = qm - m;
            kacc += ls - ql + (__expf(2.f * ql) + dq * dq) * inv2e - 0.5f;
        }
        #pragma unroll
        for (int off = 32; off; off >>= 1) kacc += __shfl_xor(kacc, off);
        if (l == 0) logqp0p[bid] = kacc / (float)B;
    }
}

// ---------------------------------------------------------------- action/x part of z_enc
__global__ __launch_bounds__(64) void ax_kernel(const float* __restrict__ xs, const float* __restrict__ actions,
                          const float* __restrict__ aw, const float* __restrict__ ab,
                          float* __restrict__ ax) {
    int bid = blockIdx.x;            // (t*E + e)*NBG + bg
    int bg = bid % NBG; int te = bid / NBG; int e = te % E; int t = te / E;
    int tid = threadIdx.x;           // 64
    __shared__ float xrow[BGRP][D];
    __shared__ float arow[BGRP][A];
    for (int i = tid; i < BGRP * D; i += 64) {
        int j = i / D, d = i % D;
        xrow[j][d] = xs[((size_t)e * S + (size_t)t * B + bg * BGRP + j) * D + d];
    }
    for (int i = tid; i < BGRP * A; i += 64) {
        int j = i / A, a = i % A;
        arow[j][a] = actions[((size_t)e * S + (size_t)t * B + bg * BGRP + j) * A + a];
    }
    __syncthreads();
    int l = tid;
    float acc[BGRP];
    float bias = ab[e * L + l];
    #pragma unroll
    for (int j = 0; j < BGRP; ++j) acc[j] = bias;
    const float* awp = aw + ((size_t)e * FLAT + L) * L + l;
    #pragma unroll 4
    for (int a = 0; a < A; ++a) {
        float wv = awp[(size_t)a * L];
        #pragma unroll
        for (int j = 0; j < BGRP; ++j) acc[j] += arow[j][a] * wv;
    }
    const float* xwp = aw + ((size_t)e * FLAT + L + A) * L + l;
    #pragma unroll 4
    for (int d = 0; d < D; ++d) {
        float wv = xwp[(size_t)d * L];
        #pragma unroll
        for (int j = 0; j < BGRP; ++j) acc[j] += xrow[j][d] * wv;
    }
    size_t rbase = (size_t)t * RTOT + e * B + bg * BGRP;
    #pragma unroll
    for (int j = 0; j < BGRP; ++j) ax[(rbase + j) * L + l] = acc[j];
}

// ---------------------------------------------------------------- sequential SDE loop (MFMA)
__global__ __launch_bounds__(512) void seq_kernel(
    const float* __restrict__ awPk, const float* __restrict__ dW,
    const float* __restrict__ z0buf, const float* __restrict__ axbuf,
    const unsigned short* __restrict__ pk1, const unsigned short* __restrict__ pk2,
    const unsigned short* __restrict__ pk3,
    const float* __restrict__ fb1, const float* __restrict__ hb1,
    const float* __restrict__ fb2, const float* __restrict__ hb2,
    const float* __restrict__ fb3, const float* __restrict__ hb3,
    const float* __restrict__ gtab, float* __restrict__ z_all, float* __restrict__ rowlr)
{
    __shared__ __align__(16) float Z[RPB][L], zc[RPB][L], zhA[RPB][L], zhB[RPB][L], dwS[RPB][L];
    __shared__ float fzb[2][RPB][L], gzb[2][RPB][L];
    __shared__ float fh[2 * RPB * L];
    __shared__ float lfb[2][RPB], lcS[RPB], lrsum[RPB];
    __shared__ __align__(16) unsigned short ybf[RPB * L];
    __shared__ __align__(16) unsigned short o1[2 * RPB * H], o2[2 * RPB * H];

    int tid = threadIdx.x;
    int r_base = blockIdx.x * RPB;
    int wv = tid >> 6;               // 0..7
    int lane = tid & 63;

    for (int i = tid; i < RPB * L; i += 512)
        Z[i >> 6][i & 63] = z0buf[(size_t)r_base * L + i];
    if (tid < RPB) lrsum[tid] = 0.f;
    __syncthreads();

    // ---- drift: y (bf16 swizzled in ybf; fp32 in ysrc) -> fzb[bo], gzb[bo], lfb[bo]
    auto drift = [&](const float (*ysrc)[L], int bo) {
        int net = wv >> 2;
        int nt0 = (wv & 3) << 2;
        int rA = lane & 15, kg = lane >> 4;
        // ---- stage a: y[16][64] @ w1[64][256]
        {
            bf16x8 A0 = *(const bf16x8*)&ybf[((rA << 6) + (kg << 3)) ^ ((rA & 7) << 3)];
            bf16x8 A1 = *(const bf16x8*)&ybf[((rA << 6) + 32 + (kg << 3)) ^ ((rA & 7) << 3)];
            const bf16x8* Bp = (const bf16x8*)(pk1 + net * 16384);
            const float* b1 = net ? hb1 : fb1;
            unsigned short* o1n = o1 + net * 4096;
            #pragma unroll
            for (int i = 0; i < 4; ++i) {
                int n = nt0 + i;
                float bias = b1[(n << 4) + rA];
                f32x4 acc = {bias, bias, bias, bias};
                acc = MFMA16(A0, Bp[(n * 2 + 0) * 64 + lane], acc);
                acc = MFMA16(A1, Bp[(n * 2 + 1) * 64 + lane], acc);
                int c = (n << 4) + rA;
                #pragma unroll
                for (int rr = 0; rr < 4; ++rr) {
                    int r = (kg << 2) + rr;
                    o1n[((r << 8) + c) ^ ((r & 7) << 3)] = f2bf(sigf(acc[rr]));
                }
            }
        }
        __syncthreads();
        // ---- stage b: h1[16][256] @ w2[256][256]
        {
            const unsigned short* o1n = o1 + net * 4096;
            bf16x8 Ab[8];
            #pragma unroll
            for (int kc = 0; kc < 8; ++kc)
                Ab[kc] = *(const bf16x8*)&o1n[((rA << 8) + (kc << 5) + (kg << 3)) ^ ((rA & 7) << 3)];
            const bf16x8* Bp = (const bf16x8*)(pk2 + net * 65536);
            const float* b2 = net ? hb2 : fb2;
            unsigned short* o2n = o2 + net * 4096;
            #pragma unroll
            for (int i = 0; i < 4; ++i) {
                int n = nt0 + i;
                float bias = b2[(n << 4) + rA];
                f32x4 acc = {bias, bias, bias, bias};
                #pragma unroll
                for (int kc = 0; kc < 8; ++kc)
                    acc = MFMA16(Ab[kc], Bp[(n * 8 + kc) * 64 + lane], acc);
                int c = (n << 4) + rA;
                #pragma unroll
                for (int rr = 0; rr < 4; ++rr) {
                    int r = (kg << 2) + rr;
                    o2n[((r << 8) + c) ^ ((r & 7) << 3)] = f2bf(sigf(acc[rr]));
                }
            }
        }
        __syncthreads();
        // ---- stage c: h2[16][256] @ w3[256][64]  (wave -> (net = wv>>2, n = wv&3))
        {
            int cnet = wv >> 2, n = wv & 3;
            const unsigned short* o2n = o2 + cnet * 4096;
            const bf16x8* Bp = (const bf16x8*)(pk3 + cnet * 16384);
            const float* b3 = cnet ? hb3 : fb3;
            float bias = b3[(n << 4) + rA];
            f32x4 acc = {bias, bias, bias, bias};
            #pragma unroll
            for (int kc = 0; kc < 8; ++kc) {
                bf16x8 Ac = *(const bf16x8*)&o2n[((rA << 8) + (kc << 5) + (kg << 3)) ^ ((rA & 7) << 3)];
                acc = MFMA16(Ac, Bp[(n * 8 + kc) * 64 + lane], acc);
            }
            float* fhn = fh + cnet * (RPB * L);
            int c = (n << 4) + rA;
            #pragma unroll
            for (int rr = 0; rr < 4; ++rr)
                fhn[(((kg << 2) + rr) << 6) + c] = acc[rr];
        }
        __syncthreads();
        // ---- finalize: g table, u, lf (wave wv -> rows wv, wv+8)
        #pragma unroll
        for (int pass = 0; pass < 2; ++pass) {
            int r = wv + (pass << 3);
            int l = lane;
            float fv = fh[(r << 6) + l];
            float hv = fh[(RPB * L) + (r << 6) + l];
            float yl = ysrc[r][l];
            float x = (yl - GYMIN) * GINVDY;
            x = fminf(fmaxf(x, 0.0f), (float)(GNT - 2) + 0.999f);
            int ii = (int)x;
            float fr = x - (float)ii;
            const float* tl = gtab + ((size_t)l << 12);
            float gv = tl[ii] * (1.0f - fr) + tl[ii + 1] * fr;
            float u = (fv - hv) / gv;
            fzb[bo][r][l] = fv;
            gzb[bo][r][l] = gv;
            float us = u * u;
            #pragma unroll
            for (int off = 32; off; off >>= 1) us += __shfl_xor(us, off);
            if (l == 0) lfb[bo][r] = 0.5f * us;
        }
        __syncthreads();
    };

    for (int t = 0; t < T; ++t) {
        // z_enc = Z @ act_w[:, :L] + precomputed action/x part
        for (int i = tid; i < RPB * L; i += 512) {
            int r = i >> 6, l = i & 63;
            int e = (r_base + r) / B;
            float a = axbuf[((size_t)t * RTOT + r_base) * L + i];
            float bsum = 0.f;
            const float4* aw4 = (const float4*)awPk + (e << 10) + l;
            const float4* zp = (const float4*)(&Z[r][0]);
            #pragma unroll 4
            for (int q = 0; q < 16; ++q) {
                float4 w = aw4[q * 64];
                float4 u = zp[q];
                a += w.x * u.x; bsum += w.y * u.y; a += w.z * u.z; bsum += w.w * u.w;
            }
            float v = a + bsum;
            zc[r][l] = v;
            zhA[r][l] = v;
            ybf[i ^ ((r & 7) << 3)] = f2bf(v);
        }
        if (tid < RPB) lcS[tid] = 0.f;
        __syncthreads();

        drift(zc, 0);

        float (*zh)[L] = zhA;
        float (*zt)[L] = zhB;
        int cur = 0;
        #pragma unroll
        for (int k = 0; k < NSUB; ++k) {
            int nxt = cur ^ 1;
            for (int i = tid; i < RPB * L; i += 512) {
                int r = i >> 6, l = i & 63;
                float dwv = dW[((size_t)(t * NSUB + k) * RTOT + r_base) * L + i] * SQDT;
                dwS[r][l] = dwv;
                float v = 2.f * zc[r][l] - zh[r][l]
                        + fzb[cur][r][l] * DT + gzb[cur][r][l] * dwv;
                zt[r][l] = v;
                ybf[i ^ ((r & 7) << 3)] = f2bf(v);
            }
            __syncthreads();
            drift(zt, nxt);
            for (int i = tid; i < RPB * L; i += 512) {
                int r = i >> 6, l = i & 63;
                zc[r][l] += 0.5f * (fzb[cur][r][l] + fzb[nxt][r][l]) * DT
                          + 0.5f * (gzb[cur][r][l] + gzb[nxt][r][l]) * dwS[r][l];
            }
            if (tid < RPB) lcS[tid] += 0.5f * (lfb[cur][tid] + lfb[nxt][tid]) * DT;
            { float (*tmp)[L] = zh; zh = zt; zt = tmp; }
            cur = nxt;
            __syncthreads();
        }
        for (int i = tid; i < RPB * L; i += 512) {
            int r = i >> 6, l = i & 63;
            Z[r][l] = zc[r][l];
            z_all[((size_t)t * RTOT + r_base) * L + i] = zc[r][l];
        }
        if (tid < RPB) lrsum[tid] += lcS[tid];
        __syncthreads();
    }
    if (tid < RPB) rowlr[r_base + tid] = lrsum[tid];
}

// ---------------------------------------------------------------- projection
__global__ __launch_bounds__(256) void proj_kernel(const float* __restrict__ z_all,
                            const float* __restrict__ pw1, const float* __restrict__ pb1,
                            const float* __restrict__ pw2, const float* __restrict__ pb2,
                            const float* __restrict__ pw3, const float* __restrict__ pb3,
                            float* __restrict__ out) {
    int bid = blockIdx.x;            // (t*E + e)*NBG + bg
    int bg = bid % NBG; int te = bid / NBG; int e = te % E; int t = te / E;
    int tid = threadIdx.x;           // 256
    __shared__ float zs[BGRP][L];
    __shared__ float p1s[BGRP][H];
    __shared__ float p2s[BGRP][H];
    __shared__ float part3[D][BGRP];
    size_t rbase = (size_t)t * RTOT + e * B + bg * BGRP;
    for (int i = tid; i < BGRP * L; i += 256) {
        int j = i >> 6, ll = i & 63;
        zs[j][ll] = z_all[(rbase + j) * L + ll];
    }
    __syncthreads();
    {
        float bias = pb1[e * H + tid];
        float acc[BGRP];
        #pragma unroll
        for (int j = 0; j < BGRP; ++j) acc[j] = bias;
        const float* w = pw1 + (size_t)e * L * H + tid;
        #pragma unroll 4
        for (int k = 0; k < L; ++k) {
            float wv = w[(size_t)k * H];
            #pragma unroll
            for (int j = 0; j < BGRP; ++j) acc[j] += zs[j][k] * wv;
        }
        #pragma unroll
        for (int j = 0; j < BGRP; ++j) p1s[j][tid] = sigf(acc[j]);
    }
    __syncthreads();
    {
        float bias = pb2[e * H + tid];
        float acc[BGRP];
        #pragma unroll
        for (int j = 0; j < BGRP; ++j) acc[j] = bias;
        const float* w = pw2 + (size_t)e * H * H + tid;
        #pragma unroll 4
        for (int k = 0; k < H; ++k) {
            float wv = w[(size_t)k * H];
            #pragma unroll
            for (int j = 0; j < BGRP; ++j) acc[j] += p1s[j][k] * wv;
        }
        #pragma unroll
        for (int j = 0; j < BGRP; ++j) p2s[j][tid] = sigf(acc[j]);
    }
    __syncthreads();
    float acc3[BGRP];
    {
        int dd = tid & 127, kh = tid >> 7;
        #pragma unroll
        for (int j = 0; j < BGRP; ++j) acc3[j] = 0.f;
        const float* w = pw3 + (size_t)e * H * D + dd;
        #pragma unroll 4
        for (int k = kh * 128; k < kh * 128 + 128; ++k) {
            float wv = w[(size_t)k * D];
            #pragma unroll
            for (int j = 0; j < BGRP; ++j) acc3[j] += p2s[j][k] * wv;
        }
        if (kh == 1) {
            #pragma unroll
            for (int j = 0; j < BGRP; ++j) part3[dd][j] = acc3[j];
        }
    }
    __syncthreads();
    if (tid < D) {
        float bias = pb3[e * D + tid];
        #pragma unroll
        for (int j = 0; j < BGRP; ++j) {
            out[8 + ((size_t)e * S + (size_t)t * B + bg * BGRP + j) * D + tid]
                = acc3[j] + part3[tid][j] + bias;
        }
    }
}

// ---------------------------------------------------------------- final combine
__global__ void fin_kernel(const float* __restrict__ logqp0p, const float* __restrict__ rowlr,
                           float* __restrict__ out) {
    int e = threadIdx.x;
    if (e < E) {
        float acc = 0.f;
        for (int t = 0; t < T; ++t)
            for (int bg = 0; bg < NBG; ++bg)
                acc += logqp0p[(t * E + e) * NBG + bg];
        float s = 0.f;
        for (int b = 0; b < B; ++b) s += rowlr[e * B + b];
        out[e] = acc + s / (float)B;
    }
}

extern "C" void kernel_launch(void* const* d_in, const int* in_sizes, int n_in,
                              void* d_out, int out_size, void* d_ws, size_t ws_size,
                              hipStream_t stream) {
    const float* xs      = (const float*)d_in[0];
    const float* actions = (const float*)d_in[1];
    const float* z0n     = (const float*)d_in[2];
    const float* dWp     = (const float*)d_in[3];
    const float* ew1     = (const float*)d_in[4];
    const float* eb1     = (const float*)d_in[5];
    const float* ew2     = (const float*)d_in[6];
    const float* eb2     = (const float*)d_in[7];
    const float* qw      = (const float*)d_in[8];
    const float* qb      = (const float*)d_in[9];
    const float* aw      = (const float*)d_in[10];
    const float* ab      = (const float*)d_in[11];
    const float* fw1     = (const float*)d_in[12];
    const float* fb1     = (const float*)d_in[13];
    const float* fw2     = (const float*)d_in[14];
    const float* fb2     = (const float*)d_in[15];
    const float* fw3     = (const float*)d_in[16];
    const float* fb3     = (const float*)d_in[17];
    const float* hw1     = (const float*)d_in[18];
    const float* hb1     = (const float*)d_in[19];
    const float* hw2     = (const float*)d_in[20];
    const float* hb2     = (const float*)d_in[21];
    const float* hw3     = (const float*)d_in[22];
    const float* hb3     = (const float*)d_in[23];
    const float* gw1     = (const float*)d_in[24];
    const float* gb1     = (const float*)d_in[25];
    const float* gw2     = (const float*)d_in[26];
    const float* gb2     = (const float*)d_in[27];
    const float* pw1     = (const float*)d_in[28];
    const float* pb1     = (const float*)d_in[29];
    const float* pw2     = (const float*)d_in[30];
    const float* pb2     = (const float*)d_in[31];
    const float* pw3     = (const float*)d_in[32];
    const float* pb3     = (const float*)d_in[33];
    const float* pm      = (const float*)d_in[34];
    const float* pl      = (const float*)d_in[35];

    float* ws      = (float*)d_ws;
    float* z0buf   = ws;                       // 25600
    float* axbuf   = z0buf + 25600;            // 3072000
    float* z_all   = axbuf + 3072000;          // 3072000
    float* logqp0p = z_all + 3072000;          // 4800
    float* rowlr   = logqp0p + 4800;           // 400
    float* gtab    = rowlr + 400;              // 262144
    float* awPk    = gtab + 262144;            // 32768
    unsigned short* pku = (unsigned short*)(awPk + 32768);
    unsigned short* pk1 = pku;                 // 2*16384 ushorts
    unsigned short* pk2 = pk1 + 32768;         // 2*65536
    unsigned short* pk3 = pk2 + 131072;        // 2*16384
    float* out     = (float*)d_out;

    packB_kernel<<<64,  256, 0, stream>>>(fw1, pk1,          64, 256);
    packB_kernel<<<64,  256, 0, stream>>>(hw1, pk1 + 16384,  64, 256);
    packB_kernel<<<256, 256, 0, stream>>>(fw2, pk2,          256, 256);
    packB_kernel<<<256, 256, 0, stream>>>(hw2, pk2 + 65536,  256, 256);
    packB_kernel<<<64,  256, 0, stream>>>(fw3, pk3,          256, 64);
    packB_kernel<<<64,  256, 0, stream>>>(hw3, pk3 + 16384,  256, 64);
    packA_kernel<<<128, 256, 0, stream>>>(aw, awPk);
    gtab_kernel<<<1024, 256, 0, stream>>>(gw1, gb1, gw2, gb2, gtab);
    enc_kernel<<<T * E * NBG, 256, 0, stream>>>(xs, z0n, ew1, eb1, ew2, eb2, qw, qb, pm, pl, z0buf, logqp0p);
    ax_kernel<<<T * E * NBG, 64, 0, stream>>>(xs, actions, aw, ab, axbuf);
    seq_kernel<<<NBLK, 512, 0, stream>>>(awPk, dWp, z0buf, axbuf,
                                         pk1, pk2, pk3,
                                         fb1, hb1, fb2, hb2, fb3, hb3,
                                         gtab, z_all, rowlr);
    proj_kernel<<<T * E * NBG, 256, 0, stream>>>(z_all, pw1, pb1, pw2, pb2, pw3, pb3, out);
    fin_kernel<<<1, 64, 0, stream>>>(logqp0p, rowlr, out);
}

// Round 4
// 3154.575 us; speedup vs baseline: 4.1135x; 1.4531x over previous
//
#include <hip/hip_runtime.h>
#include <math.h>

#define E 8
#define S 6000
#define D 128
#define A 16
#define L 64
#define H 256
#define C 64
#define B 50
#define T 120
#define NSUB 2
#define FLAT 208      // L + A + D
#define RTOT 400      // E * B
#define RPB 10
#define NBLK (RTOT / RPB)   // 40, 5 blocks per e
#define BGRP 10
#define NBG 5

#define DT 0.5f
#define SQDT 0.70710678118654752440f

#define GNT 4096
#define GYMIN (-128.0f)
#define GDY 0.0625f
#define GINVDY 16.0f

typedef __attribute__((ext_vector_type(8))) short bf16x8;
typedef __attribute__((ext_vector_type(4))) float f32x4;

#define MFMA16(a, b, c) __builtin_amdgcn_mfma_f32_16x16x32_bf16(a, b, c, 0, 0, 0)

__device__ __forceinline__ float sigf(float x) { return 1.0f / (1.0f + __expf(-x)); }

__device__ __forceinline__ unsigned short f2bf(float x) {
    union { float f; unsigned u; } v; v.f = x;
    unsigned r = (v.u + 0x7FFFu + ((v.u >> 16) & 1u)) >> 16;
    return (unsigned short)r;
}

// ---------------------------------------------------------------- g table
__global__ void gtab_kernel(const float* __restrict__ gw1, const float* __restrict__ gb1,
                            const float* __restrict__ gw2, const float* __restrict__ gb2,
                            float* __restrict__ tab) {
    int idx = blockIdx.x * blockDim.x + threadIdx.x;
    if (idx >= L * GNT) return;
    int l = idx / GNT, i = idx % GNT;
    float y = GYMIN + (float)i * GDY;
    const float* w1 = gw1 + l * H;
    const float* b1 = gb1 + l * H;
    const float* w2 = gw2 + l * H;
    float acc = gb2[l];
    #pragma unroll 4
    for (int h = 0; h < H; ++h) acc += w2[h] * sigf(y * w1[h] + b1[h]);
    tab[idx] = acc;
}

// ---------------------------------------------------------------- B-fragment pack (bf16)
// src fp32 [K][N] -> dst bf16 fragment order: dst[((n*(K/32)+kc)*64 + lane)*8 + j]
//   = src[kc*32 + (lane>>4)*8 + j][n*16 + (lane&15)]
__global__ void packB_kernel(const float* __restrict__ src, unsigned short* __restrict__ dst,
                             int K, int N) {
    int idx = blockIdx.x * 256 + threadIdx.x;
    if (idx >= K * N) return;
    int j = idx & 7;
    int lane = (idx >> 3) & 63;
    int t2 = idx >> 9;               // n*(K/32) + kc
    int KC = K >> 5;
    int kc = t2 % KC, n = t2 / KC;
    int k = (kc << 5) + ((lane >> 4) << 3) + j;
    int c = (n << 4) + (lane & 15);
    dst[idx] = f2bf(src[k * N + c]);
}

// act_w z-rows per e -> bf16 fragments: dst[e*4096 + ((n*2+kc)*64 + lane)*8 + j]
__global__ void packAW_kernel(const float* __restrict__ aw, unsigned short* __restrict__ dst) {
    int idx = blockIdx.x * 256 + threadIdx.x;
    if (idx >= E * L * L) return;
    int e = idx >> 12;
    int rem = idx & 4095;
    int j = rem & 7;
    int lane = (rem >> 3) & 63;
    int t2 = rem >> 9;               // n*2 + kc
    int kc = t2 & 1, n = t2 >> 1;
    int k = (kc << 5) + ((lane >> 4) << 3) + j;
    int c = (n << 4) + (lane & 15);
    dst[idx] = f2bf(aw[((size_t)e * FLAT + k) * L + c]);
}

// ---------------------------------------------------------------- encoder + KL (+ z0 at t=0)
__global__ __launch_bounds__(256) void enc_kernel(const float* __restrict__ xs, const float* __restrict__ z0n,
                           const float* __restrict__ ew1, const float* __restrict__ eb1,
                           const float* __restrict__ ew2, const float* __restrict__ eb2,
                           const float* __restrict__ qw,  const float* __restrict__ qb,
                           const float* __restrict__ pm,  const float* __restrict__ pl,
                           float* __restrict__ z0buf, float* __restrict__ logqp0p) {
    int bid = blockIdx.x;            // (t*E + e)*NBG + bg
    int bg = bid % NBG; int te = bid / NBG; int e = te % E; int t = te / E;
    int tid = threadIdx.x;           // 256
    __shared__ float xsh[BGRP][D];
    __shared__ float c1s[BGRP][H];
    __shared__ float part[4][C][BGRP];
    __shared__ float ctxs[BGRP][C];
    __shared__ float qs[BGRP][2 * L];

    for (int i = tid; i < BGRP * D; i += 256) {
        int j = i / D, d = i % D;
        xsh[j][d] = xs[((size_t)e * S + (size_t)t * B + bg * BGRP + j) * D + d];
    }
    __syncthreads();
    {
        float bias = eb1[e * H + tid];
        float acc[BGRP];
        #pragma unroll
        for (int j = 0; j < BGRP; ++j) acc[j] = bias;
        const float* w = ew1 + (size_t)e * D * H + tid;
        #pragma unroll 4
        for (int d = 0; d < D; ++d) {
            float wv = w[(size_t)d * H];
            #pragma unroll
            for (int j = 0; j < BGRP; ++j) acc[j] += xsh[j][d] * wv;
        }
        #pragma unroll
        for (int j = 0; j < BGRP; ++j) c1s[j][tid] = sigf(acc[j]);
    }
    __syncthreads();
    {
        int c = tid & 63, kq = tid >> 6;
        float acc[BGRP];
        #pragma unroll
        for (int j = 0; j < BGRP; ++j) acc[j] = 0.f;
        const float* w = ew2 + (size_t)e * H * C + c;
        #pragma unroll 4
        for (int h = kq * 64; h < kq * 64 + 64; ++h) {
            float wv = w[(size_t)h * C];
            #pragma unroll
            for (int j = 0; j < BGRP; ++j) acc[j] += c1s[j][h] * wv;
        }
        #pragma unroll
        for (int j = 0; j < BGRP; ++j) part[kq][c][j] = acc[j];
    }
    __syncthreads();
    if (tid < C) {
        float bias = eb2[e * C + tid];
        #pragma unroll
        for (int j = 0; j < BGRP; ++j)
            ctxs[j][tid] = part[0][tid][j] + part[1][tid][j] + part[2][tid][j] + part[3][tid][j] + bias;
    }
    __syncthreads();
    if (tid < 2 * L) {
        float bias = qb[e * 2 * L + tid];
        float acc[BGRP];
        #pragma unroll
        for (int j = 0; j < BGRP; ++j) acc[j] = bias;
        const float* w = qw + (size_t)e * C * 2 * L + tid;
        #pragma unroll 4
        for (int c = 0; c < C; ++c) {
            float wv = w[(size_t)c * 2 * L];
            #pragma unroll
            for (int j = 0; j < BGRP; ++j) acc[j] += ctxs[j][c] * wv;
        }
        #pragma unroll
        for (int j = 0; j < BGRP; ++j) qs[j][tid] = acc[j];
    }
    __syncthreads();
    if (tid < L) {
        int l = tid;
        float kacc = 0.f;
        float m = pm[e * L + l], ls = pl[e * L + l];
        float inv2e = 1.0f / (2.0f * __expf(2.0f * ls));
        #pragma unroll
        for (int j = 0; j < BGRP; ++j) {
            float qm = qs[j][l], ql = qs[j][L + l];
            if (t == 0) {
                int b = bg * BGRP + j;
                float n = z0n[((size_t)e * B + b) * L + l];
                z0buf[((size_t)e * B + b) * L + l] = qm + __expf(ql) * n;
            }
            float dq = qm - m;
            kacc += ls - ql + (__expf(2.f * ql) + dq * dq) * inv2e - 0.5f;
        }
        #pragma unroll
        for (int off = 32; off; off >>= 1) kacc += __shfl_xor(kacc, off);
        if (l == 0) logqp0p[bid] = kacc / (float)B;
    }
}

// ---------------------------------------------------------------- action/x part of z_enc
__global__ __launch_bounds__(64) void ax_kernel(const float* __restrict__ xs, const float* __restrict__ actions,
                          const float* __restrict__ aw, const float* __restrict__ ab,
                          float* __restrict__ ax) {
    int bid = blockIdx.x;            // (t*E + e)*NBG + bg
    int bg = bid % NBG; int te = bid / NBG; int e = te % E; int t = te / E;
    int tid = threadIdx.x;           // 64
    __shared__ float xrow[BGRP][D];
    __shared__ float arow[BGRP][A];
    for (int i = tid; i < BGRP * D; i += 64) {
        int j = i / D, d = i % D;
        xrow[j][d] = xs[((size_t)e * S + (size_t)t * B + bg * BGRP + j) * D + d];
    }
    for (int i = tid; i < BGRP * A; i += 64) {
        int j = i / A, a = i % A;
        arow[j][a] = actions[((size_t)e * S + (size_t)t * B + bg * BGRP + j) * A + a];
    }
    __syncthreads();
    int l = tid;
    float acc[BGRP];
    float bias = ab[e * L + l];
    #pragma unroll
    for (int j = 0; j < BGRP; ++j) acc[j] = bias;
    const float* awp = aw + ((size_t)e * FLAT + L) * L + l;
    #pragma unroll 4
    for (int a = 0; a < A; ++a) {
        float wv = awp[(size_t)a * L];
        #pragma unroll
        for (int j = 0; j < BGRP; ++j) acc[j] += arow[j][a] * wv;
    }
    const float* xwp = aw + ((size_t)e * FLAT + L + A) * L + l;
    #pragma unroll 4
    for (int d = 0; d < D; ++d) {
        float wv = xwp[(size_t)d * L];
        #pragma unroll
        for (int j = 0; j < BGRP; ++j) acc[j] += xrow[j][d] * wv;
    }
    size_t rbase = (size_t)t * RTOT + e * B + bg * BGRP;
    #pragma unroll
    for (int j = 0; j < BGRP; ++j) ax[(rbase + j) * L + l] = acc[j];
}

// ---------------------------------------------------------------- sequential SDE loop
// Weights resident: w1 in LDS, w2/w3/z_enc-w in registers. RPB=10 rows/block, 40 blocks.
__global__ __launch_bounds__(512, 2) void seq_kernel(
    const unsigned short* __restrict__ pkAW, const float* __restrict__ dW,
    const float* __restrict__ z0buf, const float* __restrict__ axbuf,
    const unsigned short* __restrict__ pk1, const unsigned short* __restrict__ pk2,
    const unsigned short* __restrict__ pk3,
    const float* __restrict__ fb1, const float* __restrict__ hb1,
    const float* __restrict__ fb2, const float* __restrict__ hb2,
    const float* __restrict__ fb3, const float* __restrict__ hb3,
    const float* __restrict__ gtab, float* __restrict__ z_all, float* __restrict__ rowlr)
{
    __shared__ __align__(16) bf16x8 w1L[4096];                 // 64 KB: stage-a weights, both nets
    __shared__ __align__(16) unsigned short ybf[16 * 64];      // 2 KB: current y (bf16, swizzled)
    __shared__ __align__(16) unsigned short o1[2][16 * 256];   // 16 KB (fh aliases o1[0..])
    __shared__ __align__(16) unsigned short o2[2][16 * 256];   // 16 KB
    __shared__ float zcS[16][64], zhA[16][64], zhB[16][64];    // 12 KB
    __shared__ float fzb[2][16][64], gzb[2][16][64];           // 16 KB
    __shared__ float lfb[2][16], lcS[16], lrsum[16];

    int tid = threadIdx.x;
    int wv = tid >> 6;               // 0..7
    int lane = tid & 63;
    int rA = lane & 15, kg = lane >> 4;
    int r_base = blockIdx.x * RPB;
    int e = blockIdx.x / 5;          // 5 blocks per e (B=50, RPB=10)
    int sw = (rA & 7) << 3;

    // ---- stage-a weights -> LDS (one-time)
    for (int i = tid; i < 4096; i += 512) w1L[i] = ((const bf16x8*)pk1)[i];

    // ---- register-resident weights
    int net = wv >> 2;               // stage a/b net
    int nt0 = (wv & 3) << 2;         // stage a/b n-tile base
    int n0 = wv & 3;                 // z_enc / stage-c n-tile
    bf16x8 W0r[2], W2r[32], W3r[8];
    {
        const bf16x8* p0 = (const bf16x8*)pkAW + (e << 9);
        #pragma unroll
        for (int kc = 0; kc < 2; ++kc) W0r[kc] = p0[(n0 * 2 + kc) * 64 + lane];
        const bf16x8* p2 = (const bf16x8*)pk2 + net * 8192;
        #pragma unroll
        for (int i2 = 0; i2 < 4; ++i2)
            #pragma unroll
            for (int kc = 0; kc < 8; ++kc)
                W2r[i2 * 8 + kc] = p2[((nt0 + i2) * 8 + kc) * 64 + lane];
        const bf16x8* p3 = (const bf16x8*)pk3 + net * 2048;
        #pragma unroll
        for (int kc = 0; kc < 8; ++kc) W3r[kc] = p3[(n0 * 8 + kc) * 64 + lane];
    }
    float biasA[4], biasB[4], biasC;
    {
        const float* b1 = net ? hb1 : fb1;
        const float* b2 = net ? hb2 : fb2;
        const float* b3 = net ? hb3 : fb3;
        #pragma unroll
        for (int i2 = 0; i2 < 4; ++i2) {
            biasA[i2] = b1[((nt0 + i2) << 4) + rA];
            biasB[i2] = b2[((nt0 + i2) << 4) + rA];
        }
        biasC = b3[(n0 << 4) + rA];
    }

    // ---- init y (bf16) from z0
    for (int i = tid; i < RPB * L; i += 512) {
        int r = i >> 6;
        ybf[i ^ ((r & 7) << 3)] = f2bf(z0buf[(size_t)r_base * L + i]);
    }
    if (tid < 16) lrsum[tid] = 0.f;
    __syncthreads();

    float* fhp = (float*)o1;         // fh[2][16][64] aliases o1 (dead between stage b and next stage a)

    auto drift = [&](const float (*__restrict__ ysrc)[64], int bo) {
        // ---- stage a: y[16][64] @ w1 -> o1 (per wave: net, 4 n-tiles)
        {
            bf16x8 A0 = *(const bf16x8*)&ybf[((rA << 6) + (kg << 3)) ^ sw];
            bf16x8 A1 = *(const bf16x8*)&ybf[((rA << 6) + 32 + (kg << 3)) ^ sw];
            f32x4 acc[4];
            #pragma unroll
            for (int i2 = 0; i2 < 4; ++i2) {
                acc[i2] = (f32x4){biasA[i2], biasA[i2], biasA[i2], biasA[i2]};
                acc[i2] = MFMA16(A0, w1L[net * 2048 + ((nt0 + i2) * 2 + 0) * 64 + lane], acc[i2]);
                acc[i2] = MFMA16(A1, w1L[net * 2048 + ((nt0 + i2) * 2 + 1) * 64 + lane], acc[i2]);
            }
            unsigned short* o1n = o1[net];
            #pragma unroll
            for (int i2 = 0; i2 < 4; ++i2) {
                int c = ((nt0 + i2) << 4) + rA;
                #pragma unroll
                for (int rr = 0; rr < 4; ++rr) {
                    int r = (kg << 2) + rr;
                    o1n[((r << 8) + c) ^ ((r & 7) << 3)] = f2bf(sigf(acc[i2][rr]));
                }
            }
        }
        __syncthreads();
        // ---- stage b: h1[16][256] @ w2 (registers) -> o2
        {
            const unsigned short* o1n = o1[net];
            f32x4 acc[4];
            #pragma unroll
            for (int i2 = 0; i2 < 4; ++i2)
                acc[i2] = (f32x4){biasB[i2], biasB[i2], biasB[i2], biasB[i2]};
            #pragma unroll
            for (int kc = 0; kc < 8; ++kc) {
                bf16x8 Ak = *(const bf16x8*)&o1n[((rA << 8) + (kc << 5) + (kg << 3)) ^ sw];
                #pragma unroll
                for (int i2 = 0; i2 < 4; ++i2)
                    acc[i2] = MFMA16(Ak, W2r[i2 * 8 + kc], acc[i2]);
            }
            unsigned short* o2n = o2[net];
            #pragma unroll
            for (int i2 = 0; i2 < 4; ++i2) {
                int c = ((nt0 + i2) << 4) + rA;
                #pragma unroll
                for (int rr = 0; rr < 4; ++rr) {
                    int r = (kg << 2) + rr;
                    o2n[((r << 8) + c) ^ ((r & 7) << 3)] = f2bf(sigf(acc[i2][rr]));
                }
            }
        }
        __syncthreads();
        // ---- stage c: h2[16][256] @ w3 (registers) -> fh (per wave: net, n0)
        {
            const unsigned short* o2n = o2[net];
            f32x4 acc = (f32x4){biasC, biasC, biasC, biasC};
            #pragma unroll
            for (int kc = 0; kc < 8; ++kc) {
                bf16x8 Ak = *(const bf16x8*)&o2n[((rA << 8) + (kc << 5) + (kg << 3)) ^ sw];
                acc = MFMA16(Ak, W3r[kc], acc);
            }
            int c = (n0 << 4) + rA;
            #pragma unroll
            for (int rr = 0; rr < 4; ++rr)
                fhp[net * 1024 + (((kg << 2) + rr) << 6) + c] = acc[rr];
        }
        __syncthreads();
        // ---- finalize: g table, u, lf (wave wv -> row wv, wv+8)
        #pragma unroll
        for (int pass = 0; pass < 2; ++pass) {
            int r = wv + (pass << 3);
            if (r < RPB) {
                int l = lane;
                float fv = fhp[(r << 6) + l];
                float hv = fhp[1024 + (r << 6) + l];
                float yl = ysrc[r][l];
                float x = (yl - GYMIN) * GINVDY;
                x = fminf(fmaxf(x, 0.0f), (float)(GNT - 2) + 0.999f);
                int ii = (int)x;
                float fr = x - (float)ii;
                const float* tl = gtab + ((size_t)l << 12);
                float gv = tl[ii] * (1.0f - fr) + tl[ii + 1] * fr;
                float u = (fv - hv) / gv;
                fzb[bo][r][l] = fv;
                gzb[bo][r][l] = gv;
                float us = u * u;
                #pragma unroll
                for (int off = 32; off; off >>= 1) us += __shfl_xor(us, off);
                if (l == 0) lfb[bo][r] = 0.5f * us;
            }
        }
        __syncthreads();
    };

    for (int t = 0; t < T; ++t) {
        // ---- prefetch dW / ax for this step into registers
        size_t axb = ((size_t)t * RTOT + r_base) * L;
        size_t db0 = ((size_t)(t * 2 + 0) * RTOT + r_base) * L;
        size_t db1 = ((size_t)(t * 2 + 1) * RTOT + r_base) * L;
        float ax0 = axbuf[axb + tid];
        float dwA0 = dW[db0 + tid] * SQDT;
        float dwB0 = dW[db1 + tid] * SQDT;
        float ax1 = 0.f, dwA1 = 0.f, dwB1 = 0.f;
        if (tid < RPB * L - 512) {
            ax1  = axbuf[axb + 512 + tid];
            dwA1 = dW[db0 + 512 + tid] * SQDT;
            dwB1 = dW[db1 + 512 + tid] * SQDT;
        }
        // ---- z_enc = z_in @ act_w[:, :L] (MFMA on waves 0-3; ybf holds z_in)
        if (wv < 4) {
            bf16x8 Z0 = *(const bf16x8*)&ybf[((rA << 6) + (kg << 3)) ^ sw];
            bf16x8 Z1 = *(const bf16x8*)&ybf[((rA << 6) + 32 + (kg << 3)) ^ sw];
            f32x4 acc = (f32x4){0.f, 0.f, 0.f, 0.f};
            acc = MFMA16(Z0, W0r[0], acc);
            acc = MFMA16(Z1, W0r[1], acc);
            int c = (n0 << 4) + rA;
            #pragma unroll
            for (int rr = 0; rr < 4; ++rr)
                zcS[(kg << 2) + rr][c] = acc[rr];
        }
        if (tid < 16) lcS[tid] = 0.f;
        __syncthreads();
        // ---- finish z_enc: add ax, set zh, refresh ybf
        {
            int r = tid >> 6, l = tid & 63;
            float v = zcS[r][l] + ax0;
            zcS[r][l] = v; zhA[r][l] = v;
            ybf[tid ^ ((r & 7) << 3)] = f2bf(v);
            if (tid < RPB * L - 512) {
                int i2 = tid + 512, r2 = i2 >> 6, l2 = i2 & 63;
                float v2 = zcS[r2][l2] + ax1;
                zcS[r2][l2] = v2; zhA[r2][l2] = v2;
                ybf[i2 ^ ((r2 & 7) << 3)] = f2bf(v2);
            }
        }
        __syncthreads();

        drift(zcS, 0);

        float (*zh)[64] = zhA;
        float (*zt)[64] = zhB;
        int cur = 0;
        #pragma unroll
        for (int k2 = 0; k2 < NSUB; ++k2) {
            int nxt = cur ^ 1;
            float dwv0 = k2 ? dwB0 : dwA0;
            float dwv1 = k2 ? dwB1 : dwA1;
            {
                int r = tid >> 6, l = tid & 63;
                float v = 2.f * zcS[r][l] - zh[r][l] + fzb[cur][r][l] * DT + gzb[cur][r][l] * dwv0;
                zt[r][l] = v;
                ybf[tid ^ ((r & 7) << 3)] = f2bf(v);
                if (tid < RPB * L - 512) {
                    int i2 = tid + 512, r2 = i2 >> 6, l2 = i2 & 63;
                    float v2 = 2.f * zcS[r2][l2] - zh[r2][l2] + fzb[cur][r2][l2] * DT + gzb[cur][r2][l2] * dwv1;
                    zt[r2][l2] = v2;
                    ybf[i2 ^ ((r2 & 7) << 3)] = f2bf(v2);
                }
            }
            __syncthreads();
            drift(zt, nxt);
            {
                int r = tid >> 6, l = tid & 63;
                zcS[r][l] += 0.5f * (fzb[cur][r][l] + fzb[nxt][r][l]) * DT
                           + 0.5f * (gzb[cur][r][l] + gzb[nxt][r][l]) * dwv0;
                if (tid < RPB * L - 512) {
                    int i2 = tid + 512, r2 = i2 >> 6, l2 = i2 & 63;
                    zcS[r2][l2] += 0.5f * (fzb[cur][r2][l2] + fzb[nxt][r2][l2]) * DT
                                 + 0.5f * (gzb[cur][r2][l2] + gzb[nxt][r2][l2]) * dwv1;
                }
            }
            if (tid < RPB) lcS[tid] += 0.5f * (lfb[cur][tid] + lfb[nxt][tid]) * DT;
            { float (*tmp)[64] = zh; zh = zt; zt = tmp; }
            cur = nxt;
            __syncthreads();
        }
        // ---- step end: store z, refresh ybf for next step's z_enc
        {
            int r = tid >> 6;
            float v = zcS[r][tid & 63];
            z_all[((size_t)t * RTOT + r_base) * L + tid] = v;
            ybf[tid ^ ((r & 7) << 3)] = f2bf(v);
            if (tid < RPB * L - 512) {
                int i2 = tid + 512, r2 = i2 >> 6;
                float v2 = zcS[r2][i2 & 63];
                z_all[((size_t)t * RTOT + r_base) * L + i2] = v2;
                ybf[i2 ^ ((r2 & 7) << 3)] = f2bf(v2);
            }
        }
        if (tid < RPB) lrsum[tid] += lcS[tid];
        __syncthreads();
    }
    if (tid < RPB) rowlr[r_base + tid] = lrsum[tid];
}

// ---------------------------------------------------------------- projection
__global__ __launch_bounds__(256) void proj_kernel(const float* __restrict__ z_all,
                            const float* __restrict__ pw1, const float* __restrict__ pb1,
                            const float* __restrict__ pw2, const float* __restrict__ pb2,
                            const float* __restrict__ pw3, const float* __restrict__ pb3,
                            float* __restrict__ out) {
    int bid = blockIdx.x;            // (t*E + e)*NBG + bg
    int bg = bid % NBG; int te = bid / NBG; int e = te % E; int t = te / E;
    int tid = threadIdx.x;           // 256
    __shared__ float zs[BGRP][L];
    __shared__ float p1s[BGRP][H];
    __shared__ float p2s[BGRP][H];
    __shared__ float part3[D][BGRP];
    size_t rbase = (size_t)t * RTOT + e * B + bg * BGRP;
    for (int i = tid; i < BGRP * L; i += 256) {
        int j = i >> 6, ll = i & 63;
        zs[j][ll] = z_all[(rbase + j) * L + ll];
    }
    __syncthreads();
    {
        float bias = pb1[e * H + tid];
        float acc[BGRP];
        #pragma unroll
        for (int j = 0; j < BGRP; ++j) acc[j] = bias;
        const float* w = pw1 + (size_t)e * L * H + tid;
        #pragma unroll 4
        for (int k = 0; k < L; ++k) {
            float wv = w[(size_t)k * H];
            #pragma unroll
            for (int j = 0; j < BGRP; ++j) acc[j] += zs[j][k] * wv;
        }
        #pragma unroll
        for (int j = 0; j < BGRP; ++j) p1s[j][tid] = sigf(acc[j]);
    }
    __syncthreads();
    {
        float bias = pb2[e * H + tid];
        float acc[BGRP];
        #pragma unroll
        for (int j = 0; j < BGRP; ++j) acc[j] = bias;
        const float* w = pw2 + (size_t)e * H * H + tid;
        #pragma unroll 4
        for (int k = 0; k < H; ++k) {
            float wv = w[(size_t)k * H];
            #pragma unroll
            for (int j = 0; j < BGRP; ++j) acc[j] += p1s[j][k] * wv;
        }
        #pragma unroll
        for (int j = 0; j < BGRP; ++j) p2s[j][tid] = sigf(acc[j]);
    }
    __syncthreads();
    float acc3[BGRP];
    {
        int dd = tid & 127, kh = tid >> 7;
        #pragma unroll
        for (int j = 0; j < BGRP; ++j) acc3[j] = 0.f;
        const float* w = pw3 + (size_t)e * H * D + dd;
        #pragma unroll 4
        for (int k = kh * 128; k < kh * 128 + 128; ++k) {
            float wv = w[(size_t)k * D];
            #pragma unroll
            for (int j = 0; j < BGRP; ++j) acc3[j] += p2s[j][k] * wv;
        }
        if (kh == 1) {
            #pragma unroll
            for (int j = 0; j < BGRP; ++j) part3[dd][j] = acc3[j];
        }
    }
    __syncthreads();
    if (tid < D) {
        float bias = pb3[e * D + tid];
        #pragma unroll
        for (int j = 0; j < BGRP; ++j) {
            out[8 + ((size_t)e * S + (size_t)t * B + bg * BGRP + j) * D + tid]
                = acc3[j] + part3[tid][j] + bias;
        }
    }
}

// ---------------------------------------------------------------- final combine
__global__ void fin_kernel(const float* __restrict__ logqp0p, const float* __restrict__ rowlr,
                           float* __restrict__ out) {
    int e = threadIdx.x;
    if (e < E) {
        float acc = 0.f;
        for (int t = 0; t < T; ++t)
            for (int bg = 0; bg < NBG; ++bg)
                acc += logqp0p[(t * E + e) * NBG + bg];
        float s = 0.f;
        for (int b = 0; b < B; ++b) s += rowlr[e * B + b];
        out[e] = acc + s / (float)B;
    }
}

extern "C" void kernel_launch(void* const* d_in, const int* in_sizes, int n_in,
                              void* d_out, int out_size, void* d_ws, size_t ws_size,
                              hipStream_t stream) {
    const float* xs      = (const float*)d_in[0];
    const float* actions = (const float*)d_in[1];
    const float* z0n     = (const float*)d_in[2];
    const float* dWp     = (const float*)d_in[3];
    const float* ew1     = (const float*)d_in[4];
    const float* eb1     = (const float*)d_in[5];
    const float* ew2     = (const float*)d_in[6];
    const float* eb2     = (const float*)d_in[7];
    const float* qw      = (const float*)d_in[8];
    const float* qb      = (const float*)d_in[9];
    const float* aw      = (const float*)d_in[10];
    const float* ab      = (const float*)d_in[11];
    const float* fw1     = (const float*)d_in[12];
    const float* fb1     = (const float*)d_in[13];
    const float* fw2     = (const float*)d_in[14];
    const float* fb2     = (const float*)d_in[15];
    const float* fw3     = (const float*)d_in[16];
    const float* fb3     = (const float*)d_in[17];
    const float* hw1     = (const float*)d_in[18];
    const float* hb1     = (const float*)d_in[19];
    const float* hw2     = (const float*)d_in[20];
    const float* hb2     = (const float*)d_in[21];
    const float* hw3     = (const float*)d_in[22];
    const float* hb3     = (const float*)d_in[23];
    const float* gw1     = (const float*)d_in[24];
    const float* gb1     = (const float*)d_in[25];
    const float* gw2     = (const float*)d_in[26];
    const float* gb2     = (const float*)d_in[27];
    const float* pw1     = (const float*)d_in[28];
    const float* pb1     = (const float*)d_in[29];
    const float* pw2     = (const float*)d_in[30];
    const float* pb2     = (const float*)d_in[31];
    const float* pw3     = (const float*)d_in[32];
    const float* pb3     = (const float*)d_in[33];
    const float* pm      = (const float*)d_in[34];
    const float* pl      = (const float*)d_in[35];

    float* ws      = (float*)d_ws;
    float* z0buf   = ws;                       // 25600
    float* axbuf   = z0buf + 25600;            // 3072000
    float* z_all   = axbuf + 3072000;          // 3072000
    float* logqp0p = z_all + 3072000;          // 4800
    float* rowlr   = logqp0p + 4800;           // 400
    float* gtab    = rowlr + 400;              // 262144
    unsigned short* pku = (unsigned short*)(gtab + 262144);
    unsigned short* pk1 = pku;                 // 2*16384
    unsigned short* pk2 = pk1 + 32768;         // 2*65536
    unsigned short* pk3 = pk2 + 131072;        // 2*16384
    unsigned short* pkAW = pk3 + 32768;        // E*4096
    float* out     = (float*)d_out;

    packB_kernel<<<64,  256, 0, stream>>>(fw1, pk1,          64, 256);
    packB_kernel<<<64,  256, 0, stream>>>(hw1, pk1 + 16384,  64, 256);
    packB_kernel<<<256, 256, 0, stream>>>(fw2, pk2,          256, 256);
    packB_kernel<<<256, 256, 0, stream>>>(hw2, pk2 + 65536,  256, 256);
    packB_kernel<<<64,  256, 0, stream>>>(fw3, pk3,          256, 64);
    packB_kernel<<<64,  256, 0, stream>>>(hw3, pk3 + 16384,  256, 64);
    packAW_kernel<<<128, 256, 0, stream>>>(aw, pkAW);
    gtab_kernel<<<1024, 256, 0, stream>>>(gw1, gb1, gw2, gb2, gtab);
    enc_kernel<<<T * E * NBG, 256, 0, stream>>>(xs, z0n, ew1, eb1, ew2, eb2, qw, qb, pm, pl, z0buf, logqp0p);
    ax_kernel<<<T * E * NBG, 64, 0, stream>>>(xs, actions, aw, ab, axbuf);
    seq_kernel<<<NBLK, 512, 0, stream>>>(pkAW, dWp, z0buf, axbuf,
                                         pk1, pk2, pk3,
                                         fb1, hb1, fb2, hb2, fb3, hb3,
                                         gtab, z_all, rowlr);
    proj_kernel<<<T * E * NBG, 256, 0, stream>>>(z_all, pw1, pb1, pw2, pb2, pw3, pb3, out);
    fin_kernel<<<1, 64, 0, stream>>>(logqp0p, rowlr, out);
}